// Round 1
// baseline (1525.993 us; speedup 1.0000x reference)
//
#include <hip/hip_runtime.h>
#include <math.h>

#define L_DIM 13
#define B_DIM 32
#define S_DIM 512
#define H_DIM 768
#define QL 20
#define DL 492            // S_DIM - QL
#define NKER 11
#define DCHUNK 128
#define NCHUNK 4          // 4*128 = 512 >= 492
#define CK 64             // k-chunk size
#define NKCH (H_DIM/CK)   // 12
#define TDB_STRIDE 130    // 128 rows + 2 pad (u32 units) -> conflict-free lane reads

__device__ __forceinline__ float bf16lo(unsigned int u){
  union {unsigned int i; float f;} c; c.i = u << 16; return c.f; }
__device__ __forceinline__ float bf16hi(unsigned int u){
  union {unsigned int i; float f;} c; c.i = u & 0xffff0000u; return c.f; }
__device__ __forceinline__ unsigned int packbf(float a, float b){
  union {float f; unsigned int i;} ca, cb; ca.f = a; cb.f = b;
  unsigned int ia = ca.i + 0x8000u;   // round-to-nearest on bf16 truncation
  unsigned int ib = cb.i + 0x8000u;
  return (ia >> 16) | (ib & 0xffff0000u);
}

__global__ __launch_bounds__(256) void zero_pooled(float* p){
  int i = blockIdx.x * 256 + threadIdx.x;
  if (i < L_DIM * B_DIM * NKER) p[i] = 0.f;
}

// one wave per q-row: compute 1/max(||q||,eps) for all (l,b,t)
__global__ __launch_bounds__(256) void prep_rnq(const float* __restrict__ hs,
                                                float* __restrict__ rnq){
  int wid = blockIdx.x * 4 + (threadIdx.x >> 6);
  int lane = threadIdx.x & 63;
  if (wid >= L_DIM * B_DIM * QL) return;
  int t = wid % QL; int lb = wid / QL;
  const float* row = hs + ((size_t)lb * S_DIM + t) * H_DIM;
  float ss = 0.f;
  #pragma unroll
  for (int m = 0; m < 3; ++m) {
    float4 v = ((const float4*)row)[lane + m * 64];
    ss += v.x*v.x + v.y*v.y + v.z*v.z + v.w*v.w;
  }
  #pragma unroll
  for (int off = 32; off; off >>= 1) ss += __shfl_down(ss, off, 64);
  if (lane == 0) rnq[wid] = 1.f / fmaxf(sqrtf(ss), 1e-8f);
}

// main: per block (l, b, d-chunk of 128 rows). Lanes own d-rows (2 each),
// q values are wave-uniform LDS broadcasts, waves partition K.
__global__ __launch_bounds__(256, 4) void main_knrm(
    const float* __restrict__ hs, const float* __restrict__ rnq,
    const float* __restrict__ mu, const float* __restrict__ sigma,
    float* __restrict__ pooled)
{
  __shared__ unsigned int tdb[32 * TDB_STRIDE];   // d chunk, bf16-pairs, [kk2][row]
  __shared__ float sqc[QL * CK];                  // q chunk fp32 [t][kk]
  __shared__ float accs[QL * DCHUNK];             // cross-wave dot accumulation
  __shared__ float dss[DCHUNK];                   // d sumsq
  __shared__ float rq[QL];
  __shared__ float pblk[NKER];

  const int dc = blockIdx.x;
  const int b  = blockIdx.y;
  const int l  = blockIdx.z;
  const int lb = l * B_DIM + b;
  const int tid = threadIdx.x;
  const int lane = tid & 63;
  const int w = tid >> 6;
  const int r0 = dc * DCHUNK;

  const float* qbase = hs + (size_t)lb * S_DIM * H_DIM;
  const float* dbase = qbase + (size_t)QL * H_DIM;

  for (int i = tid; i < QL * DCHUNK + DCHUNK; i += 256) {
    if (i < QL * DCHUNK) accs[i] = 0.f; else dss[i - QL * DCHUNK] = 0.f;
  }
  if (tid < QL)  rq[tid] = rnq[lb * QL + tid];
  if (tid < NKER) pblk[tid] = 0.f;
  __syncthreads();

  float acc0[QL], acc1[QL];
  #pragma unroll
  for (int t = 0; t < QL; ++t) { acc0[t] = 0.f; acc1[t] = 0.f; }
  float ss0 = 0.f, ss1 = 0.f;

  for (int c = 0; c < NKCH; ++c) {
    const int k0 = c * CK;
    // stage q chunk: 20 rows x 64 floats = 320 float4
    for (int i = tid; i < 320; i += 256) {
      int t = i >> 4, kk4 = (i & 15) << 2;
      float4 v = *(const float4*)(qbase + t * H_DIM + k0 + kk4);
      *(float4*)(&sqc[t * CK + kk4]) = v;
    }
    // stage d chunk: 128 rows x 64 floats, packed to bf16 pairs, transposed
    #pragma unroll
    for (int it = 0; it < 8; ++it) {
      int j = tid + it * 256;
      int irow = j >> 4, seg = j & 15;
      int grow = r0 + irow; if (grow > DL - 1) grow = DL - 1;
      float4 v = *(const float4*)(dbase + (size_t)grow * H_DIM + k0 + seg * 4);
      tdb[(2 * seg)     * TDB_STRIDE + irow] = packbf(v.x, v.y);
      tdb[(2 * seg + 1) * TDB_STRIDE + irow] = packbf(v.z, v.w);
    }
    __syncthreads();
    // compute: wave w handles kk2 in [w*8, w*8+8)
    #pragma unroll
    for (int kx = 0; kx < 8; ++kx) {
      int kk2 = w * 8 + kx;
      unsigned int u0 = tdb[kk2 * TDB_STRIDE + lane];
      unsigned int u1 = tdb[kk2 * TDB_STRIDE + lane + 64];
      float d00 = bf16lo(u0), d01 = bf16hi(u0);
      float d10 = bf16lo(u1), d11 = bf16hi(u1);
      ss0 = fmaf(d00, d00, ss0); ss0 = fmaf(d01, d01, ss0);
      ss1 = fmaf(d10, d10, ss1); ss1 = fmaf(d11, d11, ss1);
      const float* qp = &sqc[2 * kk2];
      #pragma unroll
      for (int t = 0; t < QL; ++t) {
        float q0 = qp[t * CK], q1 = qp[t * CK + 1];   // wave-uniform broadcast
        acc0[t] = fmaf(q0, d00, acc0[t]); acc0[t] = fmaf(q1, d01, acc0[t]);
        acc1[t] = fmaf(q0, d10, acc1[t]); acc1[t] = fmaf(q1, d11, acc1[t]);
      }
    }
    __syncthreads();
  }

  // merge the 4 waves' K-partials
  #pragma unroll
  for (int t = 0; t < QL; ++t) {
    atomicAdd(&accs[t * DCHUNK + lane], acc0[t]);
    atomicAdd(&accs[t * DCHUNK + lane + 64], acc1[t]);
  }
  atomicAdd(&dss[lane], ss0);
  atomicAdd(&dss[lane + 64], ss1);
  __syncthreads();

  // finalize: normalize sims, RBF kernels, pool
  {
    int slot = tid & 127;
    int tg = tid >> 7;                       // t in [tg*10, tg*10+10)
    bool valid = (r0 + slot) < DL;
    float rn = 1.f / fmaxf(sqrtf(dss[slot]), 1e-8f);
    float pool[NKER], muv[NKER], iv[NKER];
    #pragma unroll
    for (int kk = 0; kk < NKER; ++kk) {
      pool[kk] = 0.f;
      muv[kk] = mu[kk];
      float s = sigma[kk];
      iv[kk] = 0.5f / (s * s);
    }
    #pragma unroll
    for (int ti = 0; ti < 10; ++ti) {
      int t = tg * 10 + ti;
      float sim = accs[t * DCHUNK + slot] * rq[t] * rn;
      #pragma unroll
      for (int kk = 0; kk < NKER; ++kk) {
        float z = sim - muv[kk];
        pool[kk] += __expf(-z * z * iv[kk]);
      }
    }
    if (valid) {
      #pragma unroll
      for (int kk = 0; kk < NKER; ++kk) atomicAdd(&pblk[kk], pool[kk]);
    }
    __syncthreads();
    if (tid < NKER) atomicAdd(&pooled[lb * NKER + tid], pblk[tid]);
  }
}

// out[b] = b + cls(b)·W[0:768] + sum_{l',kk} pooled_all[l'][b][kk]*W[768+l'*11+kk]
// with pooled_all[0] = pooled[0] (duplicated layer), pooled_all[l'] = pooled[l'-1]
__global__ __launch_bounds__(256) void finalize_k(
    const float* __restrict__ hs, const float* __restrict__ pooled,
    const float* __restrict__ W, const float* __restrict__ bb,
    float* __restrict__ out)
{
  int b = blockIdx.x, tid = threadIdx.x;
  const float* cls = hs + ((size_t)(12 * B_DIM + b) * S_DIM) * H_DIM;  // layer 12, pos 0
  float s = 0.f;
  for (int h = tid; h < H_DIM; h += 256) s += cls[h] * W[h];
  for (int j = tid; j < (L_DIM + 1) * NKER; j += 256) {
    int lp = j / NKER, kk = j - lp * NKER;
    int src = lp ? lp - 1 : 0;
    s += pooled[(src * B_DIM + b) * NKER + kk] * W[H_DIM + j];
  }
  __shared__ float red[256];
  red[tid] = s;
  __syncthreads();
  for (int off = 128; off; off >>= 1) {
    if (tid < off) red[tid] += red[tid + off];
    __syncthreads();
  }
  if (tid == 0) out[b] = red[0] + bb[0];
}

extern "C" void kernel_launch(void* const* d_in, const int* in_sizes, int n_in,
                              void* d_out, int out_size, void* d_ws, size_t ws_size,
                              hipStream_t stream)
{
  const float* hs    = (const float*)d_in[0];
  const float* mu    = (const float*)d_in[1];
  const float* sigma = (const float*)d_in[2];
  const float* W     = (const float*)d_in[3];
  const float* bb    = (const float*)d_in[4];
  float* out = (float*)d_out;
  float* pooled = (float*)d_ws;                        // 13*32*11 floats
  float* rnq = pooled + L_DIM * B_DIM * NKER;          // 13*32*20 floats

  zero_pooled<<<dim3((L_DIM*B_DIM*NKER + 255) / 256), dim3(256), 0, stream>>>(pooled);
  prep_rnq<<<dim3((L_DIM*B_DIM*QL + 3) / 4), dim3(256), 0, stream>>>(hs, rnq);
  main_knrm<<<dim3(NCHUNK, B_DIM, L_DIM), dim3(256), 0, stream>>>(hs, rnq, mu, sigma, pooled);
  finalize_k<<<dim3(B_DIM), dim3(256), 0, stream>>>(hs, pooled, W, bb, out);
}

// Round 2
// 912.109 us; speedup vs baseline: 1.6730x; 1.6730x over previous
//
#include <hip/hip_runtime.h>
#include <math.h>

#define L_DIM 13
#define B_DIM 32
#define S_DIM 512
#define H_DIM 768
#define QL 20
#define DL 492            // S_DIM - QL
#define NKER 11
#define DCHUNK 256        // d-rows per block
#define NCHUNK 2          // 2*256 = 512 >= 492
#define CK 64             // k-chunk size
#define NKCH (H_DIM/CK)   // 12
#define TSTR 257          // uint2 units per kk4 slab (257*8B stride -> conflict-free writes)
#define SQS 68            // floats per q row in LDS (bank-spread for 4-distinct-t b128 reads)

__device__ __forceinline__ float bf16lo(unsigned int u){
  union {unsigned int i; float f;} c; c.i = u << 16; return c.f; }
__device__ __forceinline__ float bf16hi(unsigned int u){
  union {unsigned int i; float f;} c; c.i = u & 0xffff0000u; return c.f; }
__device__ __forceinline__ unsigned int packbf(float a, float b){
  union {float f; unsigned int i;} ca, cb; ca.f = a; cb.f = b;
  return ((ca.i + 0x8000u) >> 16) | ((cb.i + 0x8000u) & 0xffff0000u);
}

// One block per (l, b, d-chunk of 256 rows). Thread tile: 5 t x 4 d-rows.
// a = tid&3 selects t-group (t = a*5+j); bs = tid>>2 selects d-slot
// (rows r0+bs+64m, m<4). No K-partition -> each sim owned by one thread.
__global__ __launch_bounds__(256) void main_knrm(
    const float* __restrict__ hs,
    const float* __restrict__ mu, const float* __restrict__ sigma,
    float* __restrict__ pooled)
{
  __shared__ uint2 tdb[16 * TSTR];    // d chunk, bf16 k-quads, [kk4][row]
  __shared__ float sq[QL * SQS];      // q chunk fp32 [t][kk]
  __shared__ float qss[QL];           // q sum-of-squares (full K, fp32 exact)
  __shared__ float pblk[NKER];

  const int dc = blockIdx.x;
  const int b  = blockIdx.y;
  const int l  = blockIdx.z;
  const int lb = l * B_DIM + b;
  const int tid = threadIdx.x;
  const int a  = tid & 3;
  const int bs = tid >> 2;            // 0..63
  const int r0 = dc * DCHUNK;

  const float* qbase = hs + (size_t)lb * S_DIM * H_DIM;
  const float* dbase = qbase + (size_t)QL * H_DIM;

  if (tid < QL)   qss[tid]  = 0.f;
  if (tid < NKER) pblk[tid] = 0.f;

  float acc[5][4];
  #pragma unroll
  for (int j = 0; j < 5; ++j)
    #pragma unroll
    for (int m = 0; m < 4; ++m) acc[j][m] = 0.f;
  float ss[4] = {0.f, 0.f, 0.f, 0.f};

  const int dseg  = tid & 15;         // which k-quad this thread stages
  const int drow0 = tid >> 4;         // 0..15

  for (int c = 0; c < NKCH; ++c) {
    const int k0 = c * CK;
    __syncthreads();
    // stage q: 20 rows x 16 float4
    for (int i = tid; i < QL * 16; i += 256) {
      int t = i >> 4, seg = i & 15;
      float4 v = *(const float4*)(qbase + t * H_DIM + k0 + seg * 4);
      *(float4*)(&sq[t * SQS + seg * 4]) = v;
      atomicAdd(&qss[t], v.x*v.x + v.y*v.y + v.z*v.z + v.w*v.w);
    }
    // stage d: 256 rows x 16 k-quads, packed bf16, transposed to [kk4][row]
    #pragma unroll
    for (int it = 0; it < 16; ++it) {
      int row16 = it * 16 + drow0;
      int grow = r0 + row16; if (grow > DL - 1) grow = DL - 1;
      float4 v = *(const float4*)(dbase + (size_t)grow * H_DIM + k0 + dseg * 4);
      tdb[dseg * TSTR + row16] = make_uint2(packbf(v.x, v.y), packbf(v.z, v.w));
    }
    __syncthreads();
    // compute: per k-quad: 4 b64 (d) + 5 b128 (q) LDS reads feed 96 FMAs
    #pragma unroll 4
    for (int kk4 = 0; kk4 < 16; ++kk4) {
      uint2 du[4];
      #pragma unroll
      for (int m = 0; m < 4; ++m) du[m] = tdb[kk4 * TSTR + bs + 64 * m];
      float4 qv[5];
      #pragma unroll
      for (int j = 0; j < 5; ++j)
        qv[j] = *(const float4*)(&sq[(a * 5 + j) * SQS + kk4 * 4]);
      #pragma unroll
      for (int m = 0; m < 4; ++m) {
        float d0 = bf16lo(du[m].x), d1 = bf16hi(du[m].x);
        float d2 = bf16lo(du[m].y), d3 = bf16hi(du[m].y);
        ss[m] = fmaf(d0, d0, ss[m]); ss[m] = fmaf(d1, d1, ss[m]);
        ss[m] = fmaf(d2, d2, ss[m]); ss[m] = fmaf(d3, d3, ss[m]);
        #pragma unroll
        for (int j = 0; j < 5; ++j) {
          float t0 = fmaf(qv[j].x, d0, acc[j][m]);
          t0 = fmaf(qv[j].y, d1, t0);
          t0 = fmaf(qv[j].z, d2, t0);
          acc[j][m] = fmaf(qv[j].w, d3, t0);
        }
      }
    }
  }

  // epilogue: normalize sims, RBF kernels, pool (each sim owned by one thread)
  float muv[NKER], nl[NKER];
  #pragma unroll
  for (int kk = 0; kk < NKER; ++kk) {
    muv[kk] = mu[kk];
    float s = sigma[kk];
    nl[kk] = -0.5f / (s * s) * 1.4426950408889634f;   // exp(x) = exp2(x*log2e)
  }
  float rqv[5];
  #pragma unroll
  for (int j = 0; j < 5; ++j)
    rqv[j] = 1.f / fmaxf(sqrtf(qss[a * 5 + j]), 1e-8f);

  float pool[NKER];
  #pragma unroll
  for (int kk = 0; kk < NKER; ++kk) pool[kk] = 0.f;

  #pragma unroll
  for (int m = 0; m < 4; ++m) {
    int grow = r0 + bs + 64 * m;
    if (grow < DL) {
      float rn = 1.f / fmaxf(sqrtf(ss[m]), 1e-8f);
      #pragma unroll
      for (int j = 0; j < 5; ++j) {
        float sim = acc[j][m] * rqv[j] * rn;
        #pragma unroll
        for (int kk = 0; kk < NKER; ++kk) {
          float z = sim - muv[kk];
          pool[kk] += exp2f(z * z * nl[kk]);
        }
      }
    }
  }
  // wave-level shuffle reduce, then one LDS atomic per wave per kernel
  #pragma unroll
  for (int kk = 0; kk < NKER; ++kk) {
    float v = pool[kk];
    #pragma unroll
    for (int off = 32; off; off >>= 1) v += __shfl_down(v, off, 64);
    pool[kk] = v;
  }
  if ((tid & 63) == 0) {
    #pragma unroll
    for (int kk = 0; kk < NKER; ++kk) atomicAdd(&pblk[kk], pool[kk]);
  }
  __syncthreads();
  if (tid < NKER) pooled[(lb * NCHUNK + dc) * NKER + tid] = pblk[tid];
}

// out[b] = bias + cls(b)·W[0:768] + sum_{l',kk} pooled_all[l'][b][kk]*W[768+l'*11+kk]
// pooled_all[0] = layer 0 (duplicated), pooled_all[l'] = layer l'-1 otherwise.
__global__ __launch_bounds__(256) void finalize_k(
    const float* __restrict__ hs, const float* __restrict__ pooled,
    const float* __restrict__ W, const float* __restrict__ bb,
    float* __restrict__ out)
{
  int b = blockIdx.x, tid = threadIdx.x;
  const float* cls = hs + ((size_t)(12 * B_DIM + b) * S_DIM) * H_DIM;  // layer 12, pos 0
  float s = 0.f;
  for (int h = tid; h < H_DIM; h += 256) s += cls[h] * W[h];
  for (int j = tid; j < (L_DIM + 1) * NKER; j += 256) {
    int lp = j / NKER, kk = j - lp * NKER;
    int src = lp ? lp - 1 : 0;
    int base = ((src * B_DIM + b) * NCHUNK) * NKER + kk;
    s += (pooled[base] + pooled[base + NKER]) * W[H_DIM + j];
  }
  __shared__ float red[256];
  red[tid] = s;
  __syncthreads();
  for (int off = 128; off; off >>= 1) {
    if (tid < off) red[tid] += red[tid + off];
    __syncthreads();
  }
  if (tid == 0) out[b] = red[0] + bb[0];
}

extern "C" void kernel_launch(void* const* d_in, const int* in_sizes, int n_in,
                              void* d_out, int out_size, void* d_ws, size_t ws_size,
                              hipStream_t stream)
{
  const float* hs    = (const float*)d_in[0];
  const float* mu    = (const float*)d_in[1];
  const float* sigma = (const float*)d_in[2];
  const float* W     = (const float*)d_in[3];
  const float* bb    = (const float*)d_in[4];
  float* out = (float*)d_out;
  float* pooled = (float*)d_ws;   // 13*32*2*11 floats of partial pools

  main_knrm<<<dim3(NCHUNK, B_DIM, L_DIM), dim3(256), 0, stream>>>(hs, mu, sigma, pooled);
  finalize_k<<<dim3(B_DIM), dim3(256), 0, stream>>>(hs, pooled, W, bb, out);
}